// Round 12
// baseline (1648.480 us; speedup 1.0000x reference)
//
#include <hip/hip_runtime.h>
#include <cstdint>
#include <cstddef>

#define NB   256        // graphs
#define EPG  8192       // edge slots per graph
#define H    128
#define OUTD 10
#define ETOT (NB * EPG) // 2097152

// ---------------------------------------------------------------------------
// K1a: per-graph CSR build — DETERMINISTIC. LDS bitonic sort of keys
// (dst_local << 13 | slot): total order on unique keys, so csr order is
// (dst asc, slot asc) independent of wave timing. Dead edges -> 0xFFFFFFFF
// (sort to end, never read: cnt bounds). Histogram+scan give rowptr/cnt.
// grid = NB, block = 256.  LDS = 32K keys + 16K src + 6K scan = 54 KB.
// ---------------------------------------------------------------------------
__global__ __launch_bounds__(256) void k_csr(const int* __restrict__ e0,
                                             const int* __restrict__ e1,
                                             const int2* __restrict__ epk,
                                             int packed,
                                             int* __restrict__ csr_src,
                                             int* __restrict__ rowptr,
                                             int* __restrict__ cnt,
                                             int n)
{
    __shared__ unsigned keys[EPG];            // 32 KB
    __shared__ unsigned short srcl[EPG];      // 16 KB
    __shared__ int hcnt[512];
    __shared__ int sa[512];
    __shared__ int sb[512];
    const int b = blockIdx.x, tid = threadIdx.x;
    const int nb = b * n;

    for (int j = tid; j < n; j += 256) hcnt[j] = 0;
    __syncthreads();

    // load edges -> keys + local src; histogram (count order-independent)
    for (int e = tid; e < EPG; e += 256) {
        const int ge = b * EPG + e;
        int s, d;
        if (packed) { int2 p = epk[ge]; s = p.x; d = p.y; }
        else        { s = e0[ge]; d = e1[ge]; }
        unsigned key = 0xFFFFFFFFu;
        unsigned sl  = 0;
        if (s >= 0) {
            int dl = d - nb;
            key = ((unsigned)dl << 13) | (unsigned)e;
            sl  = (unsigned)(s - nb);
            atomicAdd(&hcnt[dl], 1);
        }
        keys[e] = key;
        srcl[e] = (unsigned short)sl;
    }
    __syncthreads();

    // Hillis-Steele inclusive scan of bucket counts (deterministic)
    for (int j = tid; j < n; j += 256) sa[j] = hcnt[j];
    __syncthreads();
    int* pa = sa; int* pb = sb;
    for (int st = 1; st < n; st <<= 1) {
        for (int j = tid; j < n; j += 256) {
            int v = pa[j];
            if (j >= st) v += pa[j - st];
            pb[j] = v;
        }
        __syncthreads();
        int* t = pa; pa = pb; pb = t;
    }
    for (int j = tid; j < n; j += 256) {
        int ex = j ? pa[j - 1] : 0;
        rowptr[nb + j] = b * EPG + ex;
        cnt[nb + j]    = hcnt[j];
    }

    // bitonic sort keys ASCENDING (unique keys -> deterministic total order)
    for (int kk = 2; kk <= EPG; kk <<= 1) {
        for (int jj = kk >> 1; jj > 0; jj >>= 1) {
            __syncthreads();
            for (int i = tid; i < EPG; i += 256) {
                int ixj = i ^ jj;
                if (ixj > i) {
                    unsigned a = keys[i], c = keys[ixj];
                    bool up = ((i & kk) == 0);
                    bool sw = up ? (a > c) : (a < c);
                    if (sw) { keys[i] = c; keys[ixj] = a; }
                }
            }
        }
    }
    __syncthreads();

    // emit csr: sorted position i <- src of slot (key & 8191)
    for (int i = tid; i < EPG; i += 256) {
        unsigned key = keys[i];
        if (key != 0xFFFFFFFFu) {
            int slot = (int)(key & 8191u);
            csr_src[b * EPG + i] = nb + (int)srcl[slot];
        }
    }
}

// ---------------------------------------------------------------------------
// K1b: dense aggregation. Per column, edges accumulate sequentially in CSR
// order = (dst, slot) order — canonical segment_sum association, and fully
// deterministic. 32 lanes x float4 = 128 cols per row; 8 rows/block.
// XCD-bijective block swizzle (mapping only). grid = Ncur/8, block = 256.
// ---------------------------------------------------------------------------
__global__ __launch_bounds__(256) void k_gather(const float4* __restrict__ xg4,
                                                const int* __restrict__ csr_src,
                                                const int* __restrict__ rowptr,
                                                const int* __restrict__ cnt,
                                                float4* __restrict__ agg4,
                                                int nwg)
{
    const int bid = blockIdx.x;
    const int wk  = (bid & 7) * (nwg >> 3) + (bid >> 3);   // bijective: nwg%8==0
    const int tid = threadIdx.x;
    const int dst = wk * 8 + (tid >> 5);
    const int c4  = tid & 31;

    const int p0 = rowptr[dst];
    const int pc = cnt[dst];
    const int* sp = csr_src + p0;

    float4 acc = make_float4(0.f, 0.f, 0.f, 0.f);
    int j = 0;
    for (; j + 4 <= pc; j += 4) {
        int s0 = sp[j], s1 = sp[j + 1], s2 = sp[j + 2], s3 = sp[j + 3];
        float4 v0 = xg4[(size_t)s0 * 32 + c4];
        float4 v1 = xg4[(size_t)s1 * 32 + c4];
        float4 v2 = xg4[(size_t)s2 * 32 + c4];
        float4 v3 = xg4[(size_t)s3 * 32 + c4];
        // sequential adds in csr (slot) order
        acc.x += v0.x; acc.y += v0.y; acc.z += v0.z; acc.w += v0.w;
        acc.x += v1.x; acc.y += v1.y; acc.z += v1.z; acc.w += v1.w;
        acc.x += v2.x; acc.y += v2.y; acc.z += v2.z; acc.w += v2.w;
        acc.x += v3.x; acc.y += v3.y; acc.z += v3.z; acc.w += v3.w;
    }
    for (; j < pc; j++) {
        float4 v = xg4[(size_t)sp[j] * 32 + c4];
        acc.x += v.x; acc.y += v.y; acc.z += v.z; acc.w += v.w;
    }
    agg4[(size_t)dst * 32 + c4] = acc;
}

// ---------------------------------------------------------------------------
// XLA/Eigen f32 fast-tanh (bit-level jax semantics).
// ---------------------------------------------------------------------------
__device__ __forceinline__ float xla_tanhf(float xin)
{
    const float plus_clamp  =  7.90531110763549805f;
    const float alpha_1  = 4.89352455891786e-03f;
    const float alpha_3  = 6.37261928875436e-04f;
    const float alpha_5  = 1.48572235717979e-05f;
    const float alpha_7  = 5.12229709037114e-08f;
    const float alpha_9  = -8.60467152213735e-11f;
    const float alpha_11 = 2.00018790482477e-13f;
    const float alpha_13 = -2.76076847742355e-16f;
    const float beta_0   = 4.89352518554385e-03f;
    const float beta_2   = 2.26843463243900e-03f;
    const float beta_4   = 1.18534705686654e-04f;
    const float beta_6   = 1.19825839466702e-06f;

    float x = fminf(fmaxf(xin, -plus_clamp), plus_clamp);
    float x2 = x * x;
    float p = fmaf(x2, alpha_13, alpha_11);
    p = fmaf(x2, p, alpha_9);
    p = fmaf(x2, p, alpha_7);
    p = fmaf(x2, p, alpha_5);
    p = fmaf(x2, p, alpha_3);
    p = fmaf(x2, p, alpha_1);
    p = x * p;
    float q = fmaf(x2, beta_6, beta_4);
    q = fmaf(x2, q, beta_2);
    q = fmaf(x2, q, beta_0);
    float r = p / q;
    return (fabsf(xin) < 0.0004f) ? xin : r;
}

// ---------------------------------------------------------------------------
// K2: h = relu(agg @ Wrel + brel + x @ Wroot)  + FUSED score/skey epilogue.
// grid = Ncur/128, block = 256.
// ---------------------------------------------------------------------------
__device__ __forceinline__ void fma4(float4& acc, float a, const float4& w)
{
    acc.x += a * w.x; acc.y += a * w.y; acc.z += a * w.z; acc.w += a * w.w;
}

__global__ __launch_bounds__(256) void k_gemm(const float* __restrict__ agg,
                                              const float* __restrict__ xg,
                                              const float* __restrict__ Wrel,
                                              const float* __restrict__ brel,
                                              const float* __restrict__ Wroot,
                                              const float* __restrict__ poolw,
                                              float* __restrict__ hout,
                                              float* __restrict__ score,
                                              unsigned int* __restrict__ skey)
{
    __shared__ float sA[128 * 16];
    __shared__ float sX[128 * 16];
    __shared__ float sWr[16 * H];
    __shared__ float sWo[16 * H];

    const int tid = threadIdx.x;
    const size_t rowbase = (size_t)blockIdx.x * 128;
    const int rt = tid >> 4;
    const int ct = tid & 15;

    float4 accA[8], accB[8];
#pragma unroll
    for (int i = 0; i < 8; i++) {
        accA[i] = make_float4(0.f, 0.f, 0.f, 0.f);
        accB[i] = make_float4(0.f, 0.f, 0.f, 0.f);
    }

    const float4* gA = (const float4*)agg;
    const float4* gX = (const float4*)xg;
    const float4* gWr = (const float4*)Wrel;
    const float4* gWo = (const float4*)Wroot;

    for (int kb = 0; kb < 8; kb++) {
        __syncthreads();
#pragma unroll
        for (int j = 0; j < 2; j++) {
            int f = tid + j * 256;
            int r = f >> 2, c4 = f & 3;
            ((float4*)sA)[f] = gA[(rowbase + r) * 32 + kb * 4 + c4];
            ((float4*)sX)[f] = gX[(rowbase + r) * 32 + kb * 4 + c4];
        }
#pragma unroll
        for (int j = 0; j < 2; j++) {
            int f = tid + j * 256;
            int r = f >> 5, c4 = f & 31;
            ((float4*)sWr)[f] = gWr[(kb * 16 + r) * 32 + c4];
            ((float4*)sWo)[f] = gWo[(kb * 16 + r) * 32 + c4];
        }
        __syncthreads();

#pragma unroll
        for (int k4 = 0; k4 < 4; k4++) {
            float4 a[8], xv[8];
#pragma unroll
            for (int i = 0; i < 8; i++) {
                int r = rt + 16 * i;
                a[i]  = ((float4*)sA)[r * 4 + k4];
                xv[i] = ((float4*)sX)[r * 4 + k4];
            }
#pragma unroll
            for (int kk = 0; kk < 4; kk++) {
                int krow = k4 * 4 + kk;
                float4 wr0 = ((float4*)sWr)[krow * 32 + ct];
                float4 wr1 = ((float4*)sWr)[krow * 32 + 16 + ct];
                float4 wo0 = ((float4*)sWo)[krow * 32 + ct];
                float4 wo1 = ((float4*)sWo)[krow * 32 + 16 + ct];
#pragma unroll
                for (int i = 0; i < 8; i++) {
                    float av  = (kk == 0) ? a[i].x  : (kk == 1) ? a[i].y  : (kk == 2) ? a[i].z  : a[i].w;
                    float xvv = (kk == 0) ? xv[i].x : (kk == 1) ? xv[i].y : (kk == 2) ? xv[i].z : xv[i].w;
                    fma4(accA[i], av,  wr0);
                    fma4(accA[i], xvv, wo0);
                    fma4(accB[i], av,  wr1);
                    fma4(accB[i], xvv, wo1);
                }
            }
        }
    }

    // pool-w slice for this lane's 8 columns + ||w||^2 (16-lane tree)
    float w0f[4], w1f[4];
    double pw = 0.0;
#pragma unroll
    for (int t = 0; t < 4; t++) {
        w0f[t] = poolw[ct * 4 + t];
        w1f[t] = poolw[64 + ct * 4 + t];
        pw += (double)w0f[t] * w0f[t] + (double)w1f[t] * w1f[t];
    }
#pragma unroll
    for (int off = 8; off; off >>= 1) pw += __shfl_xor(pw, off);
    const double inv_nrm = 1.0 / sqrt(pw);

    const float4 br0 = ((const float4*)brel)[ct];
    const float4 br1 = ((const float4*)brel)[16 + ct];
    float4* gH = (float4*)hout;
#pragma unroll
    for (int i = 0; i < 8; i++) {
        int r = rt + 16 * i;
        float4 o0, o1;
        o0.x = fmaxf(accA[i].x + br0.x, 0.f);
        o0.y = fmaxf(accA[i].y + br0.y, 0.f);
        o0.z = fmaxf(accA[i].z + br0.z, 0.f);
        o0.w = fmaxf(accA[i].w + br0.w, 0.f);
        o1.x = fmaxf(accB[i].x + br1.x, 0.f);
        o1.y = fmaxf(accB[i].y + br1.y, 0.f);
        o1.z = fmaxf(accB[i].z + br1.z, 0.f);
        o1.w = fmaxf(accB[i].w + br1.w, 0.f);
        gH[(rowbase + r) * 32 + ct]      = o0;
        gH[(rowbase + r) * 32 + 16 + ct] = o1;

        // fused score: f64 dot over the 16-lane group (fixed shfl tree order)
        double d = 0.0;
        d += (double)o0.x * w0f[0]; d += (double)o0.y * w0f[1];
        d += (double)o0.z * w0f[2]; d += (double)o0.w * w0f[3];
        d += (double)o1.x * w1f[0]; d += (double)o1.y * w1f[1];
        d += (double)o1.z * w1f[2]; d += (double)o1.w * w1f[3];
#pragma unroll
        for (int off = 8; off; off >>= 1) d += __shfl_xor(d, off);
        if (ct == 0) {
            float z  = (float)(d * inv_nrm);
            float sc = xla_tanhf(z);
            size_t gidx = rowbase + r;
            score[gidx] = sc;
            unsigned u = __float_as_uint(sc);
            u = (u & 0x80000000u) ? ~u : (u | 0x80000000u);
            skey[gidx] = u;
        }
    }
}

// ---------------------------------------------------------------------------
// K4: per-graph top-k (u64 bitonic, jax tie-break), gather, readout, edges.
// grid = NB, block = 256.
// ---------------------------------------------------------------------------
__global__ __launch_bounds__(256) void k_pool(const float* __restrict__ h,
                                              const float* __restrict__ score,
                                              const unsigned int* __restrict__ skey,
                                              const int* __restrict__ e0,
                                              const int* __restrict__ e1,
                                              int2* __restrict__ epk,
                                              int packed_in, int do_edges,
                                              float* __restrict__ xnew,
                                              float* __restrict__ g,
                                              int n, int k, int level0)
{
    __shared__ unsigned long long keys[512];
    __shared__ int   newid[512];
    __shared__ float red[512];

    const int b   = blockIdx.x;
    const int tid = threadIdx.x;

    for (int j = tid; j < n; j += 256)
        keys[j] = ((unsigned long long)skey[b * n + j] << 32) | (unsigned)(n - 1 - j);
    __syncthreads();

    for (int kk = 2; kk <= n; kk <<= 1) {
        for (int jj = kk >> 1; jj > 0; jj >>= 1) {
            for (int i = tid; i < n; i += 256) {
                int ixj = i ^ jj;
                if (ixj > i) {
                    unsigned long long a = keys[i], c = keys[ixj];
                    bool up = ((i & kk) == 0);
                    bool sw = up ? (a < c) : (a > c);
                    if (sw) { keys[i] = c; keys[ixj] = a; }
                }
            }
            __syncthreads();
        }
    }

    for (int j = tid; j < n; j += 256) newid[j] = -1;
    __syncthreads();
    for (int p = tid; p < k; p += 256) {
        int j = n - 1 - (int)(keys[p] & 0xFFFFFFFFu);
        newid[j] = p;
    }
    __syncthreads();

    const int c   = tid & 127;
    const int grp = tid >> 7;
    float sm = 0.f, mx = -3.4e38f;
    for (int p = grp; p < k; p += 2) {
        int j    = n - 1 - (int)(keys[p] & 0xFFFFFFFFu);
        int oldg = b * n + j;
        float sc = score[oldg];
        float v  = h[(size_t)oldg * H + c] * sc;
        xnew[((size_t)(b * k + p)) * H + c] = v;
        sm += v;
        mx = fmaxf(mx, v);
    }
    red[tid]       = sm;
    red[256 + tid] = mx;
    __syncthreads();
    if (tid < 128) {
        float mean = (red[tid] + red[tid + 128]) / (float)k;
        float mmax = fmaxf(red[256 + tid], red[256 + tid + 128]);
        size_t gi = (size_t)b * 256 + tid;
        if (level0) { g[gi] = mean;  g[gi + 128] = mmax; }
        else        { g[gi] += mean; g[gi + 128] += mmax; }
    }

    if (do_edges) {
        for (int e = b * EPG + tid; e < (b + 1) * EPG; e += 256) {
            int s, d;
            if (packed_in) { int2 pr = epk[e]; s = pr.x; d = pr.y; }
            else           { s = e0[e]; d = e1[e]; }
            int2 outp = make_int2(-1, -1);
            if (s >= 0) {
                int ns = newid[s - b * n];
                int nd = newid[d - b * n];
                if (ns >= 0 && nd >= 0) outp = make_int2(b * k + ns, b * k + nd);
            }
            epk[e] = outp;
        }
    }
}

// ---------------------------------------------------------------------------
// K5: out = relu(g @ W1 + b1) @ W2 + b2.  grid = NB, block = 128.
// ---------------------------------------------------------------------------
__global__ __launch_bounds__(128) void k_head(const float* __restrict__ g,
                                              const float* __restrict__ W1,
                                              const float* __restrict__ b1,
                                              const float* __restrict__ W2,
                                              const float* __restrict__ b2,
                                              float* __restrict__ out)
{
    __shared__ float hid[H];
    const int b = blockIdx.x, tid = threadIdx.x;
    float acc = b1[tid];
    const float* gr = g + (size_t)b * 256;
    for (int j = 0; j < 256; j++) acc += gr[j] * W1[j * H + tid];
    hid[tid] = fmaxf(acc, 0.f);
    __syncthreads();
    if (tid < OUTD) {
        float o = b2[tid];
        for (int hh = 0; hh < H; hh++) o += hid[hh] * W2[hh * OUTD + tid];
        out[b * OUTD + tid] = o;
    }
}

// ---------------------------------------------------------------------------
extern "C" void kernel_launch(void* const* d_in, const int* in_sizes, int n_in,
                              void* d_out, int out_size, void* d_ws, size_t ws_size,
                              hipStream_t stream)
{
    const float* x     = (const float*)d_in[0];
    const int*   ei    = (const int*)  d_in[1];
    const float* Wrel  = (const float*)d_in[2];
    const float* brel  = (const float*)d_in[3];
    const float* Wroot = (const float*)d_in[4];
    const float* poolw = (const float*)d_in[5];
    const float* W1    = (const float*)d_in[6];
    const float* b1    = (const float*)d_in[7];
    const float* W2    = (const float*)d_in[8];
    const float* b2    = (const float*)d_in[9];
    float* out = (float*)d_out;

    char* ws = (char*)d_ws;
    float* agg     = (float*)(ws);                          // 64 MiB
    float* hbuf    = (float*)(ws + 67108864);               // 64 MiB
    float* xbuf    = (float*)(ws + 134217728);              // 32 MiB
    int2*  epk     = (int2*) (ws + 167772160);              // 16 MiB
    int*   csr     = (int*)  (ws + 184549376);              // 8 MiB
    int*   rowptr  = (int*)  (ws + 192937984);              // 512 KiB
    int*   cnt     = (int*)  (ws + 193462272);              // 512 KiB
    float* score   = (float*)(ws + 193986560);              // 512 KiB
    unsigned int* skey = (unsigned int*)(ws + 194510848);   // 512 KiB
    float* g       = (float*)(ws + 195035136);              // 256 KiB

    const int ns[3] = {512, 256, 128};
    const float* xin = x;
    for (int lvl = 0; lvl < 3; lvl++) {
        const int n = ns[lvl], k = n / 2;
        const int Ncur = NB * n;
        const int nwg  = Ncur / 8;
        k_csr<<<NB, 256, 0, stream>>>(ei, ei + ETOT, epk, lvl ? 1 : 0,
                                      csr, rowptr, cnt, n);
        k_gather<<<nwg, 256, 0, stream>>>((const float4*)xin, csr, rowptr, cnt,
                                          (float4*)agg, nwg);
        k_gemm<<<Ncur / 128, 256, 0, stream>>>(agg, xin, Wrel + lvl * H * H,
                                               brel + lvl * H, Wroot + lvl * H * H,
                                               poolw + lvl * H, hbuf, score, skey);
        k_pool<<<NB, 256, 0, stream>>>(hbuf, score, skey, ei, ei + ETOT, epk,
                                       lvl ? 1 : 0, (lvl < 2) ? 1 : 0,
                                       xbuf, g, n, k, (lvl == 0) ? 1 : 0);
        xin = xbuf;
    }
    k_head<<<NB, 128, 0, stream>>>(g, W1, b1, W2, b2, out);
}

// Round 13
// 861.289 us; speedup vs baseline: 1.9140x; 1.9140x over previous
//
#include <hip/hip_runtime.h>
#include <cstdint>
#include <cstddef>

#define NB   256        // graphs
#define EPG  8192       // edge slots per graph
#define H    128
#define OUTD 10
#define ETOT (NB * EPG) // 2097152

// ---------------------------------------------------------------------------
// K1a: per-graph CSR build — DETERMINISTIC, sort-free.
// Wave w owns slot quarter [w*2048,(w+1)*2048). Phase A: per-wave per-dst
// histogram (LDS atomics, order-independent). Scan -> rowptr/cnt + stacked
// per-wave cursor bases. Phase B: 32 sequential 64-slot chunks per wave;
// stable intra-chunk rank via 64-step shfl equality loop; single-writer
// cursor advance (wave-lockstep => deterministic). Bucket order = global
// slot order == the R12 sorted order, at O(E) cost.
// grid = NB, block = 256. LDS = 8K Q + 8K cur + 4K scan = 20 KB.
// ---------------------------------------------------------------------------
__global__ __launch_bounds__(256) void k_csr(const int* __restrict__ e0,
                                             const int* __restrict__ e1,
                                             const int2* __restrict__ epk,
                                             int packed,
                                             int* __restrict__ csr_src,
                                             int* __restrict__ rowptr,
                                             int* __restrict__ cnt,
                                             int n)
{
    __shared__ int Q[4][512];      // per-wave per-dst counts
    __shared__ int cur[4][512];    // per-wave cursors (global csr positions)
    __shared__ int sa[512];
    __shared__ int sb[512];
    const int b = blockIdx.x, tid = threadIdx.x;
    const int w = tid >> 6, lane = tid & 63;
    const int nb = b * n;
    const int qbase = b * EPG + w * 2048;

    for (int j = tid; j < 4 * 512; j += 256) ((int*)Q)[j] = 0;
    __syncthreads();

    // Phase A: per-wave-quarter histogram
    for (int it = 0; it < 32; ++it) {
        int ge = qbase + it * 64 + lane;
        int s, d;
        if (packed) { int2 p = epk[ge]; s = p.x; d = p.y; }
        else        { s = e0[ge]; d = e1[ge]; }
        if (s >= 0) atomicAdd(&Q[w][d - nb], 1);
    }
    __syncthreads();

    // totals + Hillis-Steele scan -> rowptr/cnt; stack per-wave cursor bases
    for (int j = tid; j < n; j += 256)
        sa[j] = Q[0][j] + Q[1][j] + Q[2][j] + Q[3][j];
    __syncthreads();
    int* pa = sa; int* pb = sb;
    for (int st = 1; st < n; st <<= 1) {
        for (int j = tid; j < n; j += 256) {
            int v = pa[j];
            if (j >= st) v += pa[j - st];
            pb[j] = v;
        }
        __syncthreads();
        int* t = pa; pa = pb; pb = t;
    }
    for (int j = tid; j < n; j += 256) {
        int tot = Q[0][j] + Q[1][j] + Q[2][j] + Q[3][j];
        int run = b * EPG + (pa[j] - tot);      // exclusive base
        rowptr[nb + j] = run;
        cnt[nb + j]    = tot;
        cur[0][j] = run; run += Q[0][j];
        cur[1][j] = run; run += Q[1][j];
        cur[2][j] = run; run += Q[2][j];
        cur[3][j] = run;
    }
    __syncthreads();

    // Phase B: sequential chunks per wave, stable shfl-rank scatter
    for (int it = 0; it < 32; ++it) {
        int ge = qbase + it * 64 + lane;
        int s, d;
        if (packed) { int2 p = epk[ge]; s = p.x; d = p.y; }
        else        { s = e0[ge]; d = e1[ge]; }
        const bool live = (s >= 0);
        const int dl = live ? (d - nb) : (1024 + lane);   // dead: unique key
        int rank = 0, cnum = 0;
        for (int s2 = 0; s2 < 64; ++s2) {
            int bd = __shfl(dl, s2);
            bool eqb = (bd == dl);
            cnum += eqb ? 1 : 0;
            rank += (eqb && (s2 < lane)) ? 1 : 0;
        }
        if (live) {
            int pos = cur[w][dl] + rank;
            csr_src[pos] = s;
            if (rank == cnum - 1) cur[w][dl] = pos + 1;  // single writer/dst
        }
        __builtin_amdgcn_wave_barrier();   // pin LDS order across chunks
    }
}

// ---------------------------------------------------------------------------
// K1b: dense aggregation. Per column, edges accumulate sequentially in CSR
// order = (dst, slot) order — canonical segment_sum association, and fully
// deterministic. 32 lanes x float4 = 128 cols per row; 8 rows/block.
// XCD-bijective block swizzle (mapping only). grid = Ncur/8, block = 256.
// ---------------------------------------------------------------------------
__global__ __launch_bounds__(256) void k_gather(const float4* __restrict__ xg4,
                                                const int* __restrict__ csr_src,
                                                const int* __restrict__ rowptr,
                                                const int* __restrict__ cnt,
                                                float4* __restrict__ agg4,
                                                int nwg)
{
    const int bid = blockIdx.x;
    const int wk  = (bid & 7) * (nwg >> 3) + (bid >> 3);   // bijective: nwg%8==0
    const int tid = threadIdx.x;
    const int dst = wk * 8 + (tid >> 5);
    const int c4  = tid & 31;

    const int p0 = rowptr[dst];
    const int pc = cnt[dst];
    const int* sp = csr_src + p0;

    float4 acc = make_float4(0.f, 0.f, 0.f, 0.f);
    int j = 0;
    for (; j + 4 <= pc; j += 4) {
        int s0 = sp[j], s1 = sp[j + 1], s2 = sp[j + 2], s3 = sp[j + 3];
        float4 v0 = xg4[(size_t)s0 * 32 + c4];
        float4 v1 = xg4[(size_t)s1 * 32 + c4];
        float4 v2 = xg4[(size_t)s2 * 32 + c4];
        float4 v3 = xg4[(size_t)s3 * 32 + c4];
        // sequential adds in csr (slot) order
        acc.x += v0.x; acc.y += v0.y; acc.z += v0.z; acc.w += v0.w;
        acc.x += v1.x; acc.y += v1.y; acc.z += v1.z; acc.w += v1.w;
        acc.x += v2.x; acc.y += v2.y; acc.z += v2.z; acc.w += v2.w;
        acc.x += v3.x; acc.y += v3.y; acc.z += v3.z; acc.w += v3.w;
    }
    for (; j < pc; j++) {
        float4 v = xg4[(size_t)sp[j] * 32 + c4];
        acc.x += v.x; acc.y += v.y; acc.z += v.z; acc.w += v.w;
    }
    agg4[(size_t)dst * 32 + c4] = acc;
}

// ---------------------------------------------------------------------------
// XLA/Eigen f32 fast-tanh (bit-level jax semantics).
// ---------------------------------------------------------------------------
__device__ __forceinline__ float xla_tanhf(float xin)
{
    const float plus_clamp  =  7.90531110763549805f;
    const float alpha_1  = 4.89352455891786e-03f;
    const float alpha_3  = 6.37261928875436e-04f;
    const float alpha_5  = 1.48572235717979e-05f;
    const float alpha_7  = 5.12229709037114e-08f;
    const float alpha_9  = -8.60467152213735e-11f;
    const float alpha_11 = 2.00018790482477e-13f;
    const float alpha_13 = -2.76076847742355e-16f;
    const float beta_0   = 4.89352518554385e-03f;
    const float beta_2   = 2.26843463243900e-03f;
    const float beta_4   = 1.18534705686654e-04f;
    const float beta_6   = 1.19825839466702e-06f;

    float x = fminf(fmaxf(xin, -plus_clamp), plus_clamp);
    float x2 = x * x;
    float p = fmaf(x2, alpha_13, alpha_11);
    p = fmaf(x2, p, alpha_9);
    p = fmaf(x2, p, alpha_7);
    p = fmaf(x2, p, alpha_5);
    p = fmaf(x2, p, alpha_3);
    p = fmaf(x2, p, alpha_1);
    p = x * p;
    float q = fmaf(x2, beta_6, beta_4);
    q = fmaf(x2, q, beta_2);
    q = fmaf(x2, q, beta_0);
    float r = p / q;
    return (fabsf(xin) < 0.0004f) ? xin : r;
}

// ---------------------------------------------------------------------------
// K2: h = relu(agg @ Wrel + brel + x @ Wroot)  + FUSED score/skey epilogue.
// grid = Ncur/128, block = 256.
// ---------------------------------------------------------------------------
__device__ __forceinline__ void fma4(float4& acc, float a, const float4& w)
{
    acc.x += a * w.x; acc.y += a * w.y; acc.z += a * w.z; acc.w += a * w.w;
}

__global__ __launch_bounds__(256) void k_gemm(const float* __restrict__ agg,
                                              const float* __restrict__ xg,
                                              const float* __restrict__ Wrel,
                                              const float* __restrict__ brel,
                                              const float* __restrict__ Wroot,
                                              const float* __restrict__ poolw,
                                              float* __restrict__ hout,
                                              float* __restrict__ score,
                                              unsigned int* __restrict__ skey)
{
    __shared__ float sA[128 * 16];
    __shared__ float sX[128 * 16];
    __shared__ float sWr[16 * H];
    __shared__ float sWo[16 * H];

    const int tid = threadIdx.x;
    const size_t rowbase = (size_t)blockIdx.x * 128;
    const int rt = tid >> 4;
    const int ct = tid & 15;

    float4 accA[8], accB[8];
#pragma unroll
    for (int i = 0; i < 8; i++) {
        accA[i] = make_float4(0.f, 0.f, 0.f, 0.f);
        accB[i] = make_float4(0.f, 0.f, 0.f, 0.f);
    }

    const float4* gA = (const float4*)agg;
    const float4* gX = (const float4*)xg;
    const float4* gWr = (const float4*)Wrel;
    const float4* gWo = (const float4*)Wroot;

    for (int kb = 0; kb < 8; kb++) {
        __syncthreads();
#pragma unroll
        for (int j = 0; j < 2; j++) {
            int f = tid + j * 256;
            int r = f >> 2, c4 = f & 3;
            ((float4*)sA)[f] = gA[(rowbase + r) * 32 + kb * 4 + c4];
            ((float4*)sX)[f] = gX[(rowbase + r) * 32 + kb * 4 + c4];
        }
#pragma unroll
        for (int j = 0; j < 2; j++) {
            int f = tid + j * 256;
            int r = f >> 5, c4 = f & 31;
            ((float4*)sWr)[f] = gWr[(kb * 16 + r) * 32 + c4];
            ((float4*)sWo)[f] = gWo[(kb * 16 + r) * 32 + c4];
        }
        __syncthreads();

#pragma unroll
        for (int k4 = 0; k4 < 4; k4++) {
            float4 a[8], xv[8];
#pragma unroll
            for (int i = 0; i < 8; i++) {
                int r = rt + 16 * i;
                a[i]  = ((float4*)sA)[r * 4 + k4];
                xv[i] = ((float4*)sX)[r * 4 + k4];
            }
#pragma unroll
            for (int kk = 0; kk < 4; kk++) {
                int krow = k4 * 4 + kk;
                float4 wr0 = ((float4*)sWr)[krow * 32 + ct];
                float4 wr1 = ((float4*)sWr)[krow * 32 + 16 + ct];
                float4 wo0 = ((float4*)sWo)[krow * 32 + ct];
                float4 wo1 = ((float4*)sWo)[krow * 32 + 16 + ct];
#pragma unroll
                for (int i = 0; i < 8; i++) {
                    float av  = (kk == 0) ? a[i].x  : (kk == 1) ? a[i].y  : (kk == 2) ? a[i].z  : a[i].w;
                    float xvv = (kk == 0) ? xv[i].x : (kk == 1) ? xv[i].y : (kk == 2) ? xv[i].z : xv[i].w;
                    fma4(accA[i], av,  wr0);
                    fma4(accA[i], xvv, wo0);
                    fma4(accB[i], av,  wr1);
                    fma4(accB[i], xvv, wo1);
                }
            }
        }
    }

    // pool-w slice for this lane's 8 columns + ||w||^2 (16-lane tree)
    float w0f[4], w1f[4];
    double pw = 0.0;
#pragma unroll
    for (int t = 0; t < 4; t++) {
        w0f[t] = poolw[ct * 4 + t];
        w1f[t] = poolw[64 + ct * 4 + t];
        pw += (double)w0f[t] * w0f[t] + (double)w1f[t] * w1f[t];
    }
#pragma unroll
    for (int off = 8; off; off >>= 1) pw += __shfl_xor(pw, off);
    const double inv_nrm = 1.0 / sqrt(pw);

    const float4 br0 = ((const float4*)brel)[ct];
    const float4 br1 = ((const float4*)brel)[16 + ct];
    float4* gH = (float4*)hout;
#pragma unroll
    for (int i = 0; i < 8; i++) {
        int r = rt + 16 * i;
        float4 o0, o1;
        o0.x = fmaxf(accA[i].x + br0.x, 0.f);
        o0.y = fmaxf(accA[i].y + br0.y, 0.f);
        o0.z = fmaxf(accA[i].z + br0.z, 0.f);
        o0.w = fmaxf(accA[i].w + br0.w, 0.f);
        o1.x = fmaxf(accB[i].x + br1.x, 0.f);
        o1.y = fmaxf(accB[i].y + br1.y, 0.f);
        o1.z = fmaxf(accB[i].z + br1.z, 0.f);
        o1.w = fmaxf(accB[i].w + br1.w, 0.f);
        gH[(rowbase + r) * 32 + ct]      = o0;
        gH[(rowbase + r) * 32 + 16 + ct] = o1;

        // fused score: f64 dot over the 16-lane group (fixed shfl tree order)
        double d = 0.0;
        d += (double)o0.x * w0f[0]; d += (double)o0.y * w0f[1];
        d += (double)o0.z * w0f[2]; d += (double)o0.w * w0f[3];
        d += (double)o1.x * w1f[0]; d += (double)o1.y * w1f[1];
        d += (double)o1.z * w1f[2]; d += (double)o1.w * w1f[3];
#pragma unroll
        for (int off = 8; off; off >>= 1) d += __shfl_xor(d, off);
        if (ct == 0) {
            float z  = (float)(d * inv_nrm);
            float sc = xla_tanhf(z);
            size_t gidx = rowbase + r;
            score[gidx] = sc;
            unsigned u = __float_as_uint(sc);
            u = (u & 0x80000000u) ? ~u : (u | 0x80000000u);
            skey[gidx] = u;
        }
    }
}

// ---------------------------------------------------------------------------
// K4: per-graph top-k (u64 bitonic, jax tie-break), gather, readout, edges.
// grid = NB, block = 256.
// ---------------------------------------------------------------------------
__global__ __launch_bounds__(256) void k_pool(const float* __restrict__ h,
                                              const float* __restrict__ score,
                                              const unsigned int* __restrict__ skey,
                                              const int* __restrict__ e0,
                                              const int* __restrict__ e1,
                                              int2* __restrict__ epk,
                                              int packed_in, int do_edges,
                                              float* __restrict__ xnew,
                                              float* __restrict__ g,
                                              int n, int k, int level0)
{
    __shared__ unsigned long long keys[512];
    __shared__ int   newid[512];
    __shared__ float red[512];

    const int b   = blockIdx.x;
    const int tid = threadIdx.x;

    for (int j = tid; j < n; j += 256)
        keys[j] = ((unsigned long long)skey[b * n + j] << 32) | (unsigned)(n - 1 - j);
    __syncthreads();

    for (int kk = 2; kk <= n; kk <<= 1) {
        for (int jj = kk >> 1; jj > 0; jj >>= 1) {
            for (int i = tid; i < n; i += 256) {
                int ixj = i ^ jj;
                if (ixj > i) {
                    unsigned long long a = keys[i], c = keys[ixj];
                    bool up = ((i & kk) == 0);
                    bool sw = up ? (a < c) : (a > c);
                    if (sw) { keys[i] = c; keys[ixj] = a; }
                }
            }
            __syncthreads();
        }
    }

    for (int j = tid; j < n; j += 256) newid[j] = -1;
    __syncthreads();
    for (int p = tid; p < k; p += 256) {
        int j = n - 1 - (int)(keys[p] & 0xFFFFFFFFu);
        newid[j] = p;
    }
    __syncthreads();

    const int c   = tid & 127;
    const int grp = tid >> 7;
    float sm = 0.f, mx = -3.4e38f;
    for (int p = grp; p < k; p += 2) {
        int j    = n - 1 - (int)(keys[p] & 0xFFFFFFFFu);
        int oldg = b * n + j;
        float sc = score[oldg];
        float v  = h[(size_t)oldg * H + c] * sc;
        xnew[((size_t)(b * k + p)) * H + c] = v;
        sm += v;
        mx = fmaxf(mx, v);
    }
    red[tid]       = sm;
    red[256 + tid] = mx;
    __syncthreads();
    if (tid < 128) {
        float mean = (red[tid] + red[tid + 128]) / (float)k;
        float mmax = fmaxf(red[256 + tid], red[256 + tid + 128]);
        size_t gi = (size_t)b * 256 + tid;
        if (level0) { g[gi] = mean;  g[gi + 128] = mmax; }
        else        { g[gi] += mean; g[gi + 128] += mmax; }
    }

    if (do_edges) {
        for (int e = b * EPG + tid; e < (b + 1) * EPG; e += 256) {
            int s, d;
            if (packed_in) { int2 pr = epk[e]; s = pr.x; d = pr.y; }
            else           { s = e0[e]; d = e1[e]; }
            int2 outp = make_int2(-1, -1);
            if (s >= 0) {
                int ns = newid[s - b * n];
                int nd = newid[d - b * n];
                if (ns >= 0 && nd >= 0) outp = make_int2(b * k + ns, b * k + nd);
            }
            epk[e] = outp;
        }
    }
}

// ---------------------------------------------------------------------------
// K5: out = relu(g @ W1 + b1) @ W2 + b2.  grid = NB, block = 128.
// ---------------------------------------------------------------------------
__global__ __launch_bounds__(128) void k_head(const float* __restrict__ g,
                                              const float* __restrict__ W1,
                                              const float* __restrict__ b1,
                                              const float* __restrict__ W2,
                                              const float* __restrict__ b2,
                                              float* __restrict__ out)
{
    __shared__ float hid[H];
    const int b = blockIdx.x, tid = threadIdx.x;
    float acc = b1[tid];
    const float* gr = g + (size_t)b * 256;
    for (int j = 0; j < 256; j++) acc += gr[j] * W1[j * H + tid];
    hid[tid] = fmaxf(acc, 0.f);
    __syncthreads();
    if (tid < OUTD) {
        float o = b2[tid];
        for (int hh = 0; hh < H; hh++) o += hid[hh] * W2[hh * OUTD + tid];
        out[b * OUTD + tid] = o;
    }
}

// ---------------------------------------------------------------------------
extern "C" void kernel_launch(void* const* d_in, const int* in_sizes, int n_in,
                              void* d_out, int out_size, void* d_ws, size_t ws_size,
                              hipStream_t stream)
{
    const float* x     = (const float*)d_in[0];
    const int*   ei    = (const int*)  d_in[1];
    const float* Wrel  = (const float*)d_in[2];
    const float* brel  = (const float*)d_in[3];
    const float* Wroot = (const float*)d_in[4];
    const float* poolw = (const float*)d_in[5];
    const float* W1    = (const float*)d_in[6];
    const float* b1    = (const float*)d_in[7];
    const float* W2    = (const float*)d_in[8];
    const float* b2    = (const float*)d_in[9];
    float* out = (float*)d_out;

    char* ws = (char*)d_ws;
    float* agg     = (float*)(ws);                          // 64 MiB
    float* hbuf    = (float*)(ws + 67108864);               // 64 MiB
    float* xbuf    = (float*)(ws + 134217728);              // 32 MiB
    int2*  epk     = (int2*) (ws + 167772160);              // 16 MiB
    int*   csr     = (int*)  (ws + 184549376);              // 8 MiB
    int*   rowptr  = (int*)  (ws + 192937984);              // 512 KiB
    int*   cnt     = (int*)  (ws + 193462272);              // 512 KiB
    float* score   = (float*)(ws + 193986560);              // 512 KiB
    unsigned int* skey = (unsigned int*)(ws + 194510848);   // 512 KiB
    float* g       = (float*)(ws + 195035136);              // 256 KiB

    const int ns[3] = {512, 256, 128};
    const float* xin = x;
    for (int lvl = 0; lvl < 3; lvl++) {
        const int n = ns[lvl], k = n / 2;
        const int Ncur = NB * n;
        const int nwg  = Ncur / 8;
        k_csr<<<NB, 256, 0, stream>>>(ei, ei + ETOT, epk, lvl ? 1 : 0,
                                      csr, rowptr, cnt, n);
        k_gather<<<nwg, 256, 0, stream>>>((const float4*)xin, csr, rowptr, cnt,
                                          (float4*)agg, nwg);
        k_gemm<<<Ncur / 128, 256, 0, stream>>>(agg, xin, Wrel + lvl * H * H,
                                               brel + lvl * H, Wroot + lvl * H * H,
                                               poolw + lvl * H, hbuf, score, skey);
        k_pool<<<NB, 256, 0, stream>>>(hbuf, score, skey, ei, ei + ETOT, epk,
                                       lvl ? 1 : 0, (lvl < 2) ? 1 : 0,
                                       xbuf, g, n, k, (lvl == 0) ? 1 : 0);
        xin = xbuf;
    }
    k_head<<<NB, 128, 0, stream>>>(g, W1, b1, W2, b2, out);
}